// Round 2
// baseline (155.318 us; speedup 1.0000x reference)
//
#include <hip/hip_runtime.h>
#include <math.h>

#define NQ 12
#define DIM 4096
#define NL 6
#define TPB 64

// ---------------------------------------------------------------------------
// R10: single-wave blocks — zero cross-wave barriers.
//
// Mapping (canonical, at each layer start): label bit m <-> wire 11-m.
//   lane L (6 bits)  = label bits 0..5   <-> wires 11..6
//   reg  p (6 bits)  = label bits 6..11  <-> wires 5..0   (v[64] in VGPRs)
//
// Per layer: h1 = RY on wires 5..0 (reg bits, in-register); T1 = wave-local
// LDS transpose (reg<->lane swap; lane becomes label bits 6..11); h2 = RY on
// wires 11..6; merged diag D_om(l)*D_phi(l+1) (R9 algebra re-split 6/6,
// cross gray bit g5 = lam5^lam6 via h = lane&1); T2 = fold-store at
// g = gray12(label) restoring canonical mapping. Layer 0's D_phi(0) is
// folded into init (with the (-i)^popcount phase); last layer skips diag+T2
// (diagonals cannot affect |amp|^2) and the epilogue signs are lane-only:
// post-CNOT wire0 = L5, wire1 = L4^L5.
//
// Block = 1 wave => __syncthreads is just lgkmcnt-drain (no cross-wave
// stall); LDS = 32768 B exactly => 5 blocks/CU. A wave's v_pk_*_f32 occupies
// the FP32 pipe 4 cyc, so ~1.25 waves/SIMD suffice to saturate it.
// ---------------------------------------------------------------------------

// ---- d_ws layout (float offsets) ----
#define WS_WA0 0        // 64 f2 : init lane factor e^{i(phi0_lane - pi/2*pop)}
#define WS_Z0  128      // 64 f2 : init reg  factor e^{i(phi0_reg  - pi/2*pop)}
#define WS_W   256      // 5*64 f2 : merged diag lane factor (post-T1 lane)
#define WS_Z   896      // 5*2*64 f2 : merged diag reg table [l][h][p]
#define WS_RYT 2176     // 72 float4 : (c,c,s,s) per (l,wire)
// total 2464 floats = 9856 bytes

typedef float f2 __attribute__((ext_vector_type(2)));

__device__ __forceinline__ f2 pk_mul(f2 a, f2 b) {
  f2 d; asm("v_pk_mul_f32 %0, %1, %2" : "=v"(d) : "v"(a), "v"(b)); return d;
}
__device__ __forceinline__ f2 pk_fma(f2 a, f2 b, f2 c) {
  f2 d; asm("v_pk_fma_f32 %0, %1, %2, %3" : "=v"(d) : "v"(a), "v"(b), "v"(c)); return d;
}
// complex mul, both operands packed (re,im)
__device__ __forceinline__ f2 cmulp(f2 a, f2 c) {
  f2 r1, d;
  asm("v_pk_mul_f32 %0, %1, %2 op_sel:[0,0] op_sel_hi:[0,1]"
      : "=v"(r1) : "v"(a), "v"(c));
  asm("v_pk_fma_f32 %0, %1, %2, %3 op_sel:[1,1,0] op_sel_hi:[1,0,1] neg_lo:[1,0,0]"
      : "=v"(d) : "v"(a), "v"(c), "v"(r1));
  return d;
}

// RY pair update over 64 regs: a' = c*a - s*b ; b' = s*a + c*b
template<int BIT>
__device__ __forceinline__ void apply_ry64(f2 v[64], f2 cc, f2 ss) {
  #pragma unroll
  for (int j = 0; j < 64; ++j) {
    if (j & (1 << BIT)) continue;
    const int k = j | (1 << BIT);
    f2 a = v[j], b = v[k];
    f2 t1 = pk_mul(a, cc);
    f2 t2 = pk_mul(a, ss);
    f2 na; asm("v_pk_fma_f32 %0, %1, %2, %3 neg_lo:[1,0,0] neg_hi:[1,0,0]"
               : "=v"(na) : "v"(b), "v"(ss), "v"(t1));
    f2 nb = pk_fma(b, cc, t2);
    v[j] = na; v[k] = nb;
  }
}

// ---------------------------------------------------------------------------
// Prep kernel: 1 block x 256 threads, fills d_ws from w.
// w[(l*NQ + q)*3 + c], c: 0=phi, 1=theta, 2=omega. sign: bit set -> +0.5.
// ---------------------------------------------------------------------------
__global__ __launch_bounds__(256)
void qprep_kernel(const float* __restrict__ w, float* __restrict__ ws) {
  const int t = threadIdx.x;
  const float HPI = 1.57079632679489662f;

  if (t < 64) {              // WA0[u], u = label bits 0..5 <-> wires 11..6
    const int u = t;
    float f = 0.f;
    #pragma unroll
    for (int k = 0; k < 6; ++k) {
      float p = w[(0*NQ + (11-k))*3 + 0];
      f += ((u >> k) & 1) ? 0.5f*p : -0.5f*p;
    }
    f -= HPI * (float)__popc(u);
    float sv, cv; sincosf(f, &sv, &cv);
    ws[WS_WA0 + 2*u] = cv; ws[WS_WA0 + 2*u + 1] = sv;
  } else if (t < 128) {      // Z0[p], p = label bits 6..11 <-> wires 5..0
    const int p_ = t - 64;
    float f = 0.f;
    #pragma unroll
    for (int k = 0; k < 6; ++k) {
      float p = w[(0*NQ + (5-k))*3 + 0];
      f += ((p_ >> k) & 1) ? 0.5f*p : -0.5f*p;
    }
    f -= HPI * (float)__popc(p_);
    float sv, cv; sincosf(f, &sv, &cv);
    ws[WS_Z0 + 2*p_] = cv; ws[WS_Z0 + 2*p_ + 1] = sv;
  }

  // W[l][u], l=0..4, u = post-T1 lane = label bits 6..11 (u_k <-> wire 5-k):
  //   om(l) over u_k; phi(l+1) over gray bits g_{6+k} = u_k^u_{k+1} (g11=u5),
  //   wire 5-k for k=0..5 (k=5 -> wire 0).
  for (int idx = t; idx < 5*64; idx += 256) {
    const int l = idx >> 6, u = idx & 63;
    float f = 0.f;
    #pragma unroll
    for (int k = 0; k < 6; ++k) {
      float om = w[(l*NQ + (5-k))*3 + 2];
      f += ((u >> k) & 1) ? 0.5f*om : -0.5f*om;
    }
    const int gu = u ^ (u >> 1);
    #pragma unroll
    for (int k = 0; k < 6; ++k) {
      float ph = w[((l+1)*NQ + (5-k))*3 + 0];
      f += ((gu >> k) & 1) ? 0.5f*ph : -0.5f*ph;
    }
    float sv, cv; sincosf(f, &sv, &cv);
    ws[WS_W + 2*idx] = cv; ws[WS_W + 2*idx + 1] = sv;
  }

  // Z[l][h][p], p = label bits 0..5 (p_k <-> wire 11-k), h = lam6:
  //   om(l) over p_k; phi(l+1) over g_k = p_k^p_{k+1} (k<5), g5 = p5^h,
  //   wire 11-k for k=0..5 (k=5 -> wire 6).
  for (int idx = t; idx < 5*2*64; idx += 256) {
    const int l = idx >> 7, h = (idx >> 6) & 1, p_ = idx & 63;
    float f = 0.f;
    #pragma unroll
    for (int k = 0; k < 6; ++k) {
      float om = w[(l*NQ + (11-k))*3 + 2];
      f += ((p_ >> k) & 1) ? 0.5f*om : -0.5f*om;
    }
    const int gp = (p_ ^ (p_ >> 1)) ^ (h << 5);
    #pragma unroll
    for (int k = 0; k < 6; ++k) {
      float ph = w[((l+1)*NQ + (11-k))*3 + 0];
      f += ((gp >> k) & 1) ? 0.5f*ph : -0.5f*ph;
    }
    float sv, cv; sincosf(f, &sv, &cv);
    ws[WS_Z + 2*idx] = cv; ws[WS_Z + 2*idx + 1] = sv;
  }

  if (t < NL*NQ) {           // ryt: (c,c,s,s) of theta/2 per (l,wire)
    float sv, cv; sincosf(0.5f*w[t*3 + 1], &sv, &cv);
    ((float4*)(ws + WS_RYT))[t] = make_float4(cv, cv, sv, sv);
  }
}

// ---------------------------------------------------------------------------
// Main kernel: 1 wave per block, 64 amps per lane.
// Transpose address fns (8B elements, XOR swizzle keeps pairs adjacent):
//   fX(hi,lo) = lo*512 + ((hi ^ (lo&62))<<3)   (T1: write canon, read swapped)
//   fY(hi,lo) = hi*512 + ((lo ^ (hi&62))<<3)   (T2 fold-write, canon read)
// ---------------------------------------------------------------------------
__global__ __launch_bounds__(TPB, 1)
void qsim12_kernel(const float* __restrict__ x, const float* __restrict__ ws,
                   float* __restrict__ out) {
  __shared__ __align__(16) float st[2*DIM];   // 32768 B exactly
  const int L = threadIdx.x;                  // lane 0..63
  const int b = blockIdx.x;
  char* stb = (char*)st;

  // x cos/sin: lanes 0..11 compute, readlane broadcast (block == wave).
  float csx[NQ], csy[NQ];
  {
    float xv = (L < NQ) ? x[b*NQ + L] : 0.f;
    float sv, cv; sincosf(0.5f*xv, &sv, &cv);
    #pragma unroll
    for (int q = 0; q < NQ; ++q) {
      csx[q] = __int_as_float(__builtin_amdgcn_readlane(__float_as_int(cv), q));
      csy[q] = __int_as_float(__builtin_amdgcn_readlane(__float_as_int(sv), q));
    }
  }

  f2 v[64];

  // ---- Init: amp = prod(cos/sin) * (-i)^pop * e^{i phi0}; phase via tables.
  {
    float rl = 1.f;
    #pragma unroll
    for (int k = 0; k < 6; ++k)
      rl *= ((L >> k) & 1) ? csy[11-k] : csx[11-k];
    float mlo[8], mhi[8];
    #pragma unroll
    for (int pm = 0; pm < 8; ++pm) {
      float a = ((pm >> 0) & 1) ? csy[5] : csx[5];
      a *= ((pm >> 1) & 1) ? csy[4] : csx[4];
      a *= ((pm >> 2) & 1) ? csy[3] : csx[3];
      mlo[pm] = a;
      float bb = ((pm >> 0) & 1) ? csy[2] : csx[2];
      bb *= ((pm >> 1) & 1) ? csy[1] : csx[1];
      bb *= ((pm >> 2) & 1) ? csy[0] : csx[0];
      mhi[pm] = bb;
    }
    const float2 wv = *(const float2*)(ws + WS_WA0 + 2*L);
    const f2 a0 = (f2){wv.x*rl, wv.y*rl};
    #pragma unroll
    for (int p = 0; p < 64; ++p) {
      const float2 zv = *(const float2*)(ws + WS_Z0 + 2*p);
      f2 ph = cmulp(a0, (f2){zv.x, zv.y});
      const float m = mlo[p & 7] * mhi[p >> 3];
      v[p] = pk_mul(ph, (f2){m, m});
    }
  }

  #define RY6(BIT, WQ) { const float4 r = *(const float4*)(ws + WS_RYT + 4*(l*NQ + (WQ))); \
      apply_ry64<BIT>(v, (f2){r.x, r.y}, (f2){r.z, r.w}); }

  #pragma unroll 1
  for (int l = 0; l < NL; ++l) {
    if (l > 0) {
      // canonical entry load: v[r] = element(hi=r, lo=L) at fY(r, L)
      #pragma unroll
      for (int r = 0; r < 64; ++r)
        v[r] = *(const f2*)(stb + r*512 + ((L ^ (r & 62)) << 3));
    }
    // h1: reg bit k <-> label bit 6+k <-> wire 5-k
    RY6(0,5) RY6(1,4) RY6(2,3) RY6(3,2) RY6(4,1) RY6(5,0)

    // T1 write: v[r] -> fX(r, L)
    #pragma unroll
    for (int m = 0; m < 32; ++m) {
      const int idx = (2*m) ^ (L & 62);
      *(float4*)(stb + L*512 + (idx << 3)) =
          make_float4(v[2*m].x, v[2*m].y, v[2*m+1].x, v[2*m+1].y);
    }
    __syncthreads();
    // T1 read: lane L now = label bits 6..11; v[p] = element(hi=L, lo=p)
    #pragma unroll
    for (int p = 0; p < 64; ++p)
      v[p] = *(const f2*)(stb + p*512 + ((L ^ (p & 62)) << 3));

    // h2: reg bit k <-> label bit k <-> wire 11-k
    RY6(0,11) RY6(1,10) RY6(2,9) RY6(3,8) RY6(4,7) RY6(5,6)

    if (l < NL-1) {
      // merged diag D_om(l)*D_phi(l+1) at post-CNOT label gray(lambda)
      const float2 wv = *(const float2*)(ws + WS_W + (l*64 + L)*2);
      const f2 W = (f2){wv.x, wv.y};
      const float* zb = ws + WS_Z + ((l*2 + (L & 1))*64)*2;
      #pragma unroll
      for (int p0 = 0; p0 < 64; p0 += 8) {
        f2 z[8];
        #pragma unroll
        for (int q = 0; q < 8; ++q) {
          const float2 zv = *(const float2*)(zb + 2*(p0+q));
          z[q] = (f2){zv.x, zv.y};
        }
        #pragma unroll
        for (int q = 0; q < 8; ++q)
          v[p0+q] = cmulp(cmulp(v[p0+q], z[q]), W);
      }
      __syncthreads();   // all lanes' T1 reads complete before overwrite

      // T2 fold-write: element lambda -> slot g = gray12(lambda), canon layout
      //   g_hi = gray6(L) (const/thread); g_lo = gray6(p') ^ ((L&1)<<5)
      const int Gh  = (L ^ (L >> 1)) & 63;
      const int hb5 = (L & 1) << 5;
      const int gsw = Gh & 62;
      #pragma unroll
      for (int m = 0; m < 32; ++m) {
        const int glo0 = ((2*m) ^ m) ^ hb5;   // dest lo-index of p'=2m
        const int e = glo0 & ~1;
        float4 q4;
        if (m & 1) q4 = make_float4(v[2*m+1].x, v[2*m+1].y, v[2*m].x, v[2*m].y);
        else       q4 = make_float4(v[2*m].x, v[2*m].y, v[2*m+1].x, v[2*m+1].y);
        *(float4*)(stb + Gh*512 + ((e ^ gsw) << 3)) = q4;
      }
      __syncthreads();
    }
  }

  // ---- Epilogue: post-T1 mapping: lane L = label bits 6..11.
  // post-CNOT wire0 = lam11 = L5; wire1 = lam10^lam11 = L4^L5. Lane-uniform.
  float ssum = 0.f;
  #pragma unroll
  for (int p = 0; p < 64; ++p)
    ssum += v[p].x*v[p].x + v[p].y*v[p].y;
  float s0 = ((L >> 5) & 1) ? -ssum : ssum;
  float s1 = (((L >> 4) ^ (L >> 5)) & 1) ? -ssum : ssum;
  #pragma unroll
  for (int off = 32; off >= 1; off >>= 1) {
    s0 += __shfl_down(s0, off);
    s1 += __shfl_down(s1, off);
  }
  if (L == 0) { out[b*2 + 0] = s0; out[b*2 + 1] = s1; }
}

extern "C" void kernel_launch(void* const* d_in, const int* in_sizes, int n_in,
                              void* d_out, int out_size, void* d_ws, size_t ws_size,
                              hipStream_t stream) {
  const float* x = (const float*)d_in[0];      // (B, 12) f32
  const float* w = (const float*)d_in[1];      // (6, 12, 3) f32
  float* out = (float*)d_out;                  // (B, 2) f32
  float* ws = (float*)d_ws;                    // needs >= 9856 B
  int B = in_sizes[0] / NQ;
  qprep_kernel<<<1, 256, 0, stream>>>(w, ws);
  qsim12_kernel<<<B, TPB, 0, stream>>>(x, ws, out);
}